// Round 8
// baseline (215.602 us; speedup 1.0000x reference)
//
#include <hip/hip_runtime.h>
#include <math.h>

// CRF log-likelihood, B=2048, T=80, L=128 — v15: dual same-direction chains
// per wave (latency multiplexing inside one instruction stream).
//
// Evidence through v14: per-chain-step latency L ~= 3.3-5k cy is INVARIANT
// across memory strategies (v14's 7-step async LDS ring == v9's dist-1
// registers) -> the stall is the step's serial dependency structure, not
// memory. Throughput = L / (independent chains per SIMD): v8 had 4 -> ~960
// cy/chain-step; v9-v14 had 1-2. v13 (fwd+bwd per wave) died on 2 matrices
// = 256 AGPR. Fix: two chains of the SAME direction share one matrix.
//
// v15: wave w handles 4 batch rows as TWO independent chains (A: rows
// row0/row0+1, C: rows row0+2/row0+3), each 16 MFMA columns = 2 rows x 8
// replicas. Chains interleave tile-by-tile in-wave -> each fills the
// other's MFMA/VALU latency bubbles (no cross-wave phase-locking).
// Also: 4-deep accumulator MFMA chain split 2x2 + add (halves dep-depth).
// v12-style dist-2 register prefetch, issued at step bottom (~1.9 steps
// slack). No LDS/barriers in the main loop.
// Budget: Afr 128 (AGPR) + xb 128 + Bfr 32 + scalars/transients ~80
// ~= 370 < 512 @ launch_bounds(128,1). 512 blocks x 2 waves = 1024 waves
// = 1 round on 1024 SIMDs.
//
// Per-chain layout (q = lane>>4 owns states [32q,32q+32), a = lane&15):
//   D (tile mt, reg r) -> state 32q+4mt+r ; B (tile kk, elem j) -> state
//   32q+8kk+j  => next B-frag = pack of own D regs. Column a -> row a&1.
// Renorm every 4 steps (per row-parity max via shfl_xor {2,4,8,16,32},
// one-step delayed apply), per chain. Meet-in-middle fwd t=1..39 /
// bwd t=78..40; combine Z = a_39 . (E v_40) via 2KB LDS handoff.

#define CRF_B 2048
#define CRF_T 80
#define CRF_L 128

typedef __attribute__((ext_vector_type(8))) short bf16x8_t;
typedef __attribute__((ext_vector_type(4))) float f32x4_t;

__device__ __forceinline__ unsigned short bft(float f) {
    return (unsigned short)(__float_as_uint(f) >> 16);
}
// pack two f32 -> one dword of 2 bf16 (truncation), lo in bits 15:0
__device__ __forceinline__ int pack2(float lo, float hi) {
    return (int)__builtin_amdgcn_perm(__float_as_uint(hi), __float_as_uint(lo),
                                      0x07060302u);
}
#define MFMA16(A, B, C) __builtin_amdgcn_mfma_f32_16x16x32_bf16((A), (B), (C), 0, 0, 0)

__global__ __launch_bounds__(128, 1) void crf_v15_kernel(
    const float* __restrict__ x,           // [B,T,L]
    const float* __restrict__ trans,       // [L,L]
    const float* __restrict__ start_trans, // [L]
    const float* __restrict__ end_trans,   // [L]
    const int*   __restrict__ y,           // [B,T]
    float* __restrict__ out)               // [B]
{
    const int tid  = threadIdx.x;
    const int w    = tid >> 6;          // 0 = forward wave, 1 = backward wave
    const int lane = tid & 63;
    const int q    = lane >> 4;         // quad: owns states [32q, 32q+32)
    const int a    = lane & 15;         // MFMA n-column; row-in-chain = a & 1
    const int row0 = blockIdx.x * 4;

    __shared__ __attribute__((aligned(16))) float u_lds[4][132];
    __shared__ float crunB_lds[4];
    __shared__ float numb[4];

    // ---------------- numerator: wave w -> rows 2w, 2w+1 ----------------
    #pragma unroll
    for (int rr = 0; rr < 2; ++rr) {
        const int bb = row0 + 2 * w + rr;
        const int* yb = y + bb * CRF_T;
        const float* xbn = x + (size_t)bb * CRF_T * CRF_L;
        float p = 0.f;
        for (int t = lane; t < CRF_T; t += 64) {
            const int yt = yb[t];
            p += xbn[t * CRF_L + yt];
            p += (t + 1 < CRF_T) ? trans[yt * CRF_L + yb[t + 1]] : end_trans[yt];
            if (t == 0) p += start_trans[yt];
        }
        #pragma unroll
        for (int off = 1; off <= 32; off <<= 1) p += __shfl_xor(p, off);
        if (lane == 0) numb[2 * w + rr] = p;
    }

    // ---------------- A-fragments: full exp(trans), relabeled ----------------
    // out_state = 32*(a>>2) + 4*mt + (a&3), in_state = 32*q + 8*kk + j.
    // fwd: Ê = exp(trans[in][out]);  bwd: Ê = exp(trans[out][in]).
    // (Verified mapping from v9; independent of column->row assignment.)
    bf16x8_t Afr[8][4];
    {
        const int out_lo = 32 * (a >> 2) + (a & 3);
        const int in_lo  = 32 * q;
        const int so = w ? CRF_L : 1;   // stride of out_s in trans
        const int si = w ? 1 : CRF_L;   // stride of in_s  in trans
        #pragma unroll
        for (int mt = 0; mt < 8; ++mt) {
            const int ob = (out_lo + 4 * mt) * so;
            #pragma unroll
            for (int kk = 0; kk < 4; ++kk) {
                union { bf16x8_t v; unsigned short s[8]; } u;
                #pragma unroll
                for (int j = 0; j < 8; ++j) {
                    const int in_s = in_lo + 8 * kk + j;
                    u.s[j] = bft(__expf(trans[ob + in_s * si]));
                }
                Afr[mt][kk] = u.v;
            }
        }
    }

    const int t0    = w ? 79 : 0;
    const int tstep = w ? -1 : 1;
    // per-chain lane base pointers (chain A: rows row0+(a&1); C: +2)
    const float* xrA = x + (size_t)(row0 + (a & 1)) * CRF_T * CRF_L + 32 * q;
    const float* xrC = x + (size_t)(row0 + 2 + (a & 1)) * CRF_T * CRF_L + 32 * q;

    // ---------------- init: a_0 / v_79 -> packed B-frags (both chains) ----------------
    bf16x8_t BfA[4], BfC[4];
    {
        const float* bias = w ? end_trans : start_trans;
        const float* xpA = xrA + (size_t)t0 * CRF_L;
        const float* xpC = xrC + (size_t)t0 * CRF_L;
        const float* bp  = bias + 32 * q;
        #pragma unroll
        for (int kk = 0; kk < 4; ++kk) {
            union { bf16x8_t v; int wd[4]; } uA, uC;
            #pragma unroll
            for (int h = 0; h < 2; ++h) {
                const int mt = 2 * kk + h;
                const f32x4_t bv = *(const f32x4_t*)&bp[4 * mt];
                const f32x4_t xA = *(const f32x4_t*)&xpA[4 * mt];
                const f32x4_t xC = *(const f32x4_t*)&xpC[4 * mt];
                uA.wd[2 * h + 0] = pack2(__expf(bv[0] + xA[0]), __expf(bv[1] + xA[1]));
                uA.wd[2 * h + 1] = pack2(__expf(bv[2] + xA[2]), __expf(bv[3] + xA[3]));
                uC.wd[2 * h + 0] = pack2(__expf(bv[0] + xC[0]), __expf(bv[1] + xC[1]));
                uC.wd[2 * h + 1] = pack2(__expf(bv[2] + xC[2]), __expf(bv[3] + xC[3]));
            }
            BfA[kk] = uA.v;
            BfC[kk] = uC.v;
        }
    }

    // emission ping-pong (dist-2): xb?1 <- t0+/-1, xb?0 <- t0+/-2
    f32x4_t xbA0[8], xbA1[8], xbC0[8], xbC1[8];
    {
        const float* pA1 = xrA + (size_t)(t0 + tstep) * CRF_L;
        const float* pA2 = xrA + (size_t)(t0 + 2 * tstep) * CRF_L;
        const float* pC1 = xrC + (size_t)(t0 + tstep) * CRF_L;
        const float* pC2 = xrC + (size_t)(t0 + 2 * tstep) * CRF_L;
        #pragma unroll
        for (int mt = 0; mt < 8; ++mt) {
            xbA1[mt] = *(const f32x4_t*)&pA1[4 * mt];
            xbA0[mt] = *(const f32x4_t*)&pA2[4 * mt];
            xbC1[mt] = *(const f32x4_t*)&pC1[4 * mt];
            xbC0[mt] = *(const f32x4_t*)&pC2[4 * mt];
        }
    }

    float crA = 0.f, ivA = 1.f, MvA = 1.f;
    float crC = 0.f, ivC = 1.f, MvC = 1.f;
    int tcur = t0 + tstep;              // current t of this step

    // One dual-chain step. CUR/MEASURE/APPLY/PF literal 0/1; all indices
    // compile-time constant. Order: MFMA+exp+pack (tile-interleaved A/C)
    // -> Bfr rebuild -> measure shfl -> prefetch t+2 (bottom: ~1.9 steps
    // slack) -> advance.
#define CRF_STEP(CUR, MEASURE, APPLY, PF) do {                                  \
        if (APPLY) {                                                            \
            crA += __logf(MvA); ivA = __builtin_amdgcn_rcpf(MvA);               \
            crC += __logf(MvC); ivC = __builtin_amdgcn_rcpf(MvC);               \
        }                                                                       \
        float gA_ = 0.f, gC_ = 0.f;                                             \
        int bwA_[16], bwC_[16];                                                 \
        _Pragma("unroll")                                                       \
        for (int mt = 0; mt < 8; ++mt) {                                        \
            f32x4_t a0 = {0.f, 0.f, 0.f, 0.f};                                  \
            f32x4_t a1 = {0.f, 0.f, 0.f, 0.f};                                  \
            a0 = MFMA16(Afr[mt][0], BfA[0], a0);                                \
            a1 = MFMA16(Afr[mt][1], BfA[1], a1);                                \
            a0 = MFMA16(Afr[mt][2], BfA[2], a0);                                \
            a1 = MFMA16(Afr[mt][3], BfA[3], a1);                                \
            f32x4_t c0 = {0.f, 0.f, 0.f, 0.f};                                  \
            f32x4_t c1 = {0.f, 0.f, 0.f, 0.f};                                  \
            c0 = MFMA16(Afr[mt][0], BfC[0], c0);                                \
            c1 = MFMA16(Afr[mt][1], BfC[1], c1);                                \
            c0 = MFMA16(Afr[mt][2], BfC[2], c0);                                \
            c1 = MFMA16(Afr[mt][3], BfC[3], c1);                                \
            f32x4_t pA_, pC_;                                                   \
            _Pragma("unroll")                                                   \
            for (int r = 0; r < 4; ++r) {                                       \
                float eA_ = __expf(xbA##CUR[mt][r]);                            \
                float eC_ = __expf(xbC##CUR[mt][r]);                            \
                if (APPLY) { eA_ *= ivA; eC_ *= ivC; }                          \
                pA_[r] = (a0[r] + a1[r]) * eA_;                                 \
                pC_[r] = (c0[r] + c1[r]) * eC_;                                 \
            }                                                                   \
            if (MEASURE) {                                                      \
                gA_ = fmaxf(gA_, fmaxf(fmaxf(pA_[0], pA_[1]),                   \
                                       fmaxf(pA_[2], pA_[3])));                 \
                gC_ = fmaxf(gC_, fmaxf(fmaxf(pC_[0], pC_[1]),                   \
                                       fmaxf(pC_[2], pC_[3])));                 \
            }                                                                   \
            bwA_[2 * mt + 0] = pack2(pA_[0], pA_[1]);                           \
            bwA_[2 * mt + 1] = pack2(pA_[2], pA_[3]);                           \
            bwC_[2 * mt + 0] = pack2(pC_[0], pC_[1]);                           \
            bwC_[2 * mt + 1] = pack2(pC_[2], pC_[3]);                           \
        }                                                                       \
        _Pragma("unroll")                                                       \
        for (int kk = 0; kk < 4; ++kk) {                                        \
            union { int wd[4]; bf16x8_t v; } uA_, uC_;                          \
            uA_.wd[0] = bwA_[4 * kk + 0]; uA_.wd[1] = bwA_[4 * kk + 1];         \
            uA_.wd[2] = bwA_[4 * kk + 2]; uA_.wd[3] = bwA_[4 * kk + 3];         \
            uC_.wd[0] = bwC_[4 * kk + 0]; uC_.wd[1] = bwC_[4 * kk + 1];         \
            uC_.wd[2] = bwC_[4 * kk + 2]; uC_.wd[3] = bwC_[4 * kk + 3];         \
            BfA[kk] = uA_.v;                                                    \
            BfC[kk] = uC_.v;                                                    \
        }                                                                       \
        if (MEASURE) {                                                          \
            gA_ = fmaxf(gA_, __shfl_xor(gA_, 2));                               \
            gA_ = fmaxf(gA_, __shfl_xor(gA_, 4));                               \
            gA_ = fmaxf(gA_, __shfl_xor(gA_, 8));                               \
            gA_ = fmaxf(gA_, __shfl_xor(gA_, 16));                              \
            gA_ = fmaxf(gA_, __shfl_xor(gA_, 32));                              \
            MvA = gA_;                                                          \
            gC_ = fmaxf(gC_, __shfl_xor(gC_, 2));                               \
            gC_ = fmaxf(gC_, __shfl_xor(gC_, 4));                               \
            gC_ = fmaxf(gC_, __shfl_xor(gC_, 8));                               \
            gC_ = fmaxf(gC_, __shfl_xor(gC_, 16));                              \
            gC_ = fmaxf(gC_, __shfl_xor(gC_, 32));                              \
            MvC = gC_;                                                          \
        }                                                                       \
        if (PF) {                                                               \
            const float* pA_ = xrA + (size_t)(tcur + 2 * tstep) * CRF_L;        \
            const float* pC_ = xrC + (size_t)(tcur + 2 * tstep) * CRF_L;        \
            _Pragma("unroll")                                                   \
            for (int mt = 0; mt < 8; ++mt) {                                    \
                xbA##CUR[mt] = *(const f32x4_t*)&pA_[4 * mt];                   \
                xbC##CUR[mt] = *(const f32x4_t*)&pC_[4 * mt];                   \
            }                                                                   \
        }                                                                       \
        tcur += tstep;                                                          \
    } while (0)

    // ---------------- 39 dual-chain steps: fwd t=1..39, bwd t=78..40 ----------------
    // buffer parity = k & 1; measure at k = 4m+3, apply at k = 4m+4;
    // prefetch valid for k <= 37.
    for (int k4 = 0; k4 < 9; ++k4) {
        CRF_STEP(1, 0, 0, 1);   // k = 4m+1
        CRF_STEP(0, 0, 0, 1);   // k = 4m+2
        CRF_STEP(1, 1, 0, 1);   // k = 4m+3: measure
        CRF_STEP(0, 0, 1, 1);   // k = 4m+4: apply
    }
    CRF_STEP(1, 0, 0, 1);       // k = 37 (loads t=39 / t=40)
    CRF_STEP(0, 0, 0, 0);       // k = 38
    CRF_STEP(1, 0, 0, 0);       // k = 39
#undef CRF_STEP

    // ---------------- combine: Z = a_39 . (E v_40), per chain ----------------
    // BfA/BfC hold a_39 (fwd wave) / v_40 (bwd wave) in bf16.
    if (w == 1) {
        #pragma unroll
        for (int mt = 0; mt < 8; ++mt) {
            f32x4_t a0 = {0.f, 0.f, 0.f, 0.f};
            f32x4_t a1 = {0.f, 0.f, 0.f, 0.f};
            a0 = MFMA16(Afr[mt][0], BfA[0], a0);
            a1 = MFMA16(Afr[mt][1], BfA[1], a1);
            a0 = MFMA16(Afr[mt][2], BfA[2], a0);
            a1 = MFMA16(Afr[mt][3], BfA[3], a1);
            f32x4_t c0 = {0.f, 0.f, 0.f, 0.f};
            f32x4_t c1 = {0.f, 0.f, 0.f, 0.f};
            c0 = MFMA16(Afr[mt][0], BfC[0], c0);
            c1 = MFMA16(Afr[mt][1], BfC[1], c1);
            c0 = MFMA16(Afr[mt][2], BfC[2], c0);
            c1 = MFMA16(Afr[mt][3], BfC[3], c1);
            if (a < 2) {    // rows of chain A: u_lds[a], chain C: u_lds[2+a]
                f32x4_t uvA, uvC;
                #pragma unroll
                for (int r = 0; r < 4; ++r) {
                    uvA[r] = a0[r] + a1[r];
                    uvC[r] = c0[r] + c1[r];
                }
                *(f32x4_t*)&u_lds[a][32 * q + 4 * mt]     = uvA;
                *(f32x4_t*)&u_lds[2 + a][32 * q + 4 * mt] = uvC;
            }
        }
        if (a < 2 && q == 0) { crunB_lds[a] = crA; crunB_lds[2 + a] = crC; }
    }
    __syncthreads();
    if (w == 0) {
        // per chain: dot bf16 a_39 (Bf*) with u from LDS.
        // Bf*[kk] word wi half h -> state 32q + 8kk + 2wi + h.
        float sA = 0.f, sC = 0.f;
        #pragma unroll
        for (int kk = 0; kk < 4; ++kk) {
            union { bf16x8_t v; unsigned int wd[4]; } uA_, uC_;
            uA_.v = BfA[kk];
            uC_.v = BfC[kk];
            const f32x4_t a0v = *(const f32x4_t*)&u_lds[a & 1][32 * q + 8 * kk];
            const f32x4_t a1v = *(const f32x4_t*)&u_lds[a & 1][32 * q + 8 * kk + 4];
            const f32x4_t c0v = *(const f32x4_t*)&u_lds[2 + (a & 1)][32 * q + 8 * kk];
            const f32x4_t c1v = *(const f32x4_t*)&u_lds[2 + (a & 1)][32 * q + 8 * kk + 4];
            #pragma unroll
            for (int wi = 0; wi < 4; ++wi) {
                const float aLo = __uint_as_float(uA_.wd[wi] << 16);
                const float aHi = __uint_as_float(uA_.wd[wi] & 0xFFFF0000u);
                const float cLo = __uint_as_float(uC_.wd[wi] << 16);
                const float cHi = __uint_as_float(uC_.wd[wi] & 0xFFFF0000u);
                const float uaLo = (wi < 2) ? a0v[2 * wi]     : a1v[2 * wi - 4];
                const float uaHi = (wi < 2) ? a0v[2 * wi + 1] : a1v[2 * wi - 3];
                const float ucLo = (wi < 2) ? c0v[2 * wi]     : c1v[2 * wi - 4];
                const float ucHi = (wi < 2) ? c0v[2 * wi + 1] : c1v[2 * wi - 3];
                sA += aLo * uaLo + aHi * uaHi;
                sC += cLo * ucLo + cHi * ucHi;
            }
        }
        // sum over quads (the 4 q-groups partition the 128 states)
        sA += __shfl_xor(sA, 16); sA += __shfl_xor(sA, 32);
        sC += __shfl_xor(sC, 16); sC += __shfl_xor(sC, 32);
        if (a < 2 && q == 0) {
            out[row0 + a]     = numb[a]     - (crA + crunB_lds[a]     + __logf(sA));
            out[row0 + 2 + a] = numb[2 + a] - (crC + crunB_lds[2 + a] + __logf(sC));
        }
    }
}

extern "C" void kernel_launch(void* const* d_in, const int* in_sizes, int n_in,
                              void* d_out, int out_size, void* d_ws, size_t ws_size,
                              hipStream_t stream) {
    const float* x     = (const float*)d_in[0];
    const float* trans = (const float*)d_in[1];
    const float* st    = (const float*)d_in[2];
    const float* et    = (const float*)d_in[3];
    const int*   y     = (const int*)d_in[4];
    float* out = (float*)d_out;

    crf_v15_kernel<<<CRF_B / 4, 128, 0, stream>>>(x, trans, st, et, y, out);
}